// Round 1
// baseline (243.178 us; speedup 1.0000x reference)
//
#include <hip/hip_runtime.h>

// Problem constants (DHSMoEDetector): N=16384 tokens, D=768, H=768, C=2, E=20
#define N_D 768   // embedding dim = K of GEMM1
#define N_H 768   // hidden dim   = N of GEMM1
#define N_C 2
#define N_E 20
#define MT 128    // M tile (tokens)
#define NT 128    // N tile (hidden cols)
#define BK 32     // K step (matches mfma 16x16x32)

typedef __attribute__((ext_vector_type(8))) short short8;
typedef __attribute__((ext_vector_type(4))) float f32x4;

__device__ __forceinline__ unsigned short f2bf(float f) {
  // RNE fp32->bf16 (inputs finite; NaN path not needed)
  unsigned u = __builtin_bit_cast(unsigned, f);
  u += 0x7FFFu + ((u >> 16) & 1u);
  return (unsigned short)(u >> 16);
}
__device__ __forceinline__ float bf2f(unsigned short s) {
  unsigned u = ((unsigned)s) << 16;
  return __builtin_bit_cast(float, u);
}

#define GLD_LDS16(gp, lp)                                                        \
  __builtin_amdgcn_global_load_lds(                                              \
      (const __attribute__((address_space(1))) void*)(gp),                       \
      (__attribute__((address_space(3))) void*)(lp), 16, 0, 0)

// ---------------- sort-by-expert ----------------

__global__ __launch_bounds__(256) void k_hist(const int* __restrict__ cidx,
                                              int* __restrict__ counts, int n) {
  __shared__ int lc[N_E];
  if (threadIdx.x < N_E) lc[threadIdx.x] = 0;
  __syncthreads();
  for (int i = blockIdx.x * blockDim.x + threadIdx.x; i < n;
       i += gridDim.x * blockDim.x) {
    int e = cidx[i];
    e = e < 0 ? 0 : (e >= N_E ? N_E - 1 : e);
    atomicAdd(&lc[e], 1);
  }
  __syncthreads();
  if (threadIdx.x < N_E) atomicAdd(&counts[threadIdx.x], lc[threadIdx.x]);
}

__global__ void k_scan(const int* __restrict__ counts, int* __restrict__ offsets,
                       int* __restrict__ cursor) {
  if (threadIdx.x == 0) {
    int run = 0;
    for (int e = 0; e < N_E; ++e) {
      offsets[e] = run;
      cursor[e] = run;
      run += counts[e];
    }
  }
}

__global__ __launch_bounds__(256) void k_scatter(const int* __restrict__ cidx,
                                                 int* __restrict__ cursor,
                                                 int* __restrict__ sorted, int n) {
  __shared__ int lc[N_E];
  __shared__ int lbase[N_E];
  int tid = threadIdx.x;
  if (tid < N_E) lc[tid] = 0;
  __syncthreads();
  int i = blockIdx.x * blockDim.x + tid;
  int e = 0, p = 0;
  if (i < n) {
    e = cidx[i];
    e = e < 0 ? 0 : (e >= N_E ? N_E - 1 : e);
    p = atomicAdd(&lc[e], 1);
  }
  __syncthreads();
  if (tid < N_E) lbase[tid] = atomicAdd(&cursor[tid], lc[tid]);
  __syncthreads();
  if (i < n) sorted[lbase[e] + p] = i;
}

// ---------------- W1 transpose + fp32->bf16 ----------------
// W1 (E, D, H) fp32 -> W1t (E, H, D) bf16   (K-contiguous B operand)

__global__ __launch_bounds__(256) void k_w1_cvt(const float* __restrict__ W1,
                                                unsigned short* __restrict__ W1t) {
  __shared__ float tile[32][33];  // +1 pad: no bank conflicts
  int e = blockIdx.z;
  int h0 = blockIdx.x * 32, d0 = blockIdx.y * 32;
  const float* src = W1 + (size_t)e * N_D * N_H;
  unsigned short* dst = W1t + (size_t)e * N_H * N_D;
  int tx = threadIdx.x & 31, ty = threadIdx.x >> 5;
  for (int s = 0; s < 4; ++s)
    tile[ty + 8 * s][tx] = src[(size_t)(d0 + ty + 8 * s) * N_H + h0 + tx];
  __syncthreads();
  for (int s = 0; s < 4; ++s)
    dst[(size_t)(h0 + ty + 8 * s) * N_D + d0 + tx] = f2bf(tile[tx][ty + 8 * s]);
}

// ---------------- grouped GEMM1: h = relu(Xg @ W1[e] + b1[e]) ----------------
// grid: (N_H/NT, max_m_tiles, N_E). A rows gathered via sorted ids, converted
// to bf16 inline; B staged with global_load_lds width=16 (m97 structure).

__global__ __launch_bounds__(256, 2) void k_gemm1(
    const float* __restrict__ emb, const float* __restrict__ b1,
    const unsigned short* __restrict__ W1t, const int* __restrict__ sorted,
    const int* __restrict__ counts, const int* __restrict__ offsets,
    unsigned short* __restrict__ hbuf) {
  const int e = blockIdx.z;
  const int cnt = counts[e];
  const int m0 = blockIdx.y * MT;
  if (m0 >= cnt) return;
  const int off = offsets[e];
  const int n0 = blockIdx.x * NT;

  __shared__ unsigned short lA[MT * BK];  // [m][k] bf16, 8KB
  __shared__ unsigned short lB[NT * BK];  // [n][k] bf16, 8KB
  __shared__ int lRow[MT];

  const int tid = threadIdx.x;
  if (tid < MT) {
    int m = m0 + tid;
    lRow[tid] = sorted[off + (m < cnt ? m : 0)];  // clamp padding rows
  }
  __syncthreads();

  const int wid = tid >> 6, lane = tid & 63;
  const int wm = (wid >> 1) * 64, wn = (wid & 1) * 64;  // 2x2 wave grid
  const int quad = lane >> 4, lm = lane & 15;

  // A staging: 4 x float4 per thread per K-step (128 rows x 32 k fp32)
  const float4* aptr[4];
  int arow[4], akq[4];
  for (int s = 0; s < 4; ++s) {
    int g = tid + s * 256;
    arow[s] = g >> 3;
    akq[s] = g & 7;
    aptr[s] = (const float4*)(emb + (size_t)lRow[arow[s]] * N_D) + akq[s];
  }

  // B staging: 2 global_load_lds_dwordx4 per wave, 16 rows (1KB) each
  const unsigned short* Bbase = W1t + (size_t)e * N_H * N_D + (size_t)n0 * N_D;
  const unsigned short* bgp[2];
  unsigned short* blp[2];
  for (int t = 0; t < 2; ++t) {
    int r = (wid * 2 + t) * 16 + (lane >> 2);
    bgp[t] = Bbase + (size_t)r * N_D + (lane & 3) * 8;
    blp[t] = &lB[(wid * 2 + t) * 16 * BK];
  }

  f32x4 acc[4][4] = {};

  for (int kt = 0; kt < N_D / BK; ++kt) {
    __syncthreads();  // previous iter's ds_reads done before overwrite
    GLD_LDS16(bgp[0] + kt * BK, blp[0]);
    GLD_LDS16(bgp[1] + kt * BK, blp[1]);
    for (int s = 0; s < 4; ++s) {
      float4 v = aptr[s][kt * (BK / 4)];
      ushort4 b4;
      b4.x = f2bf(v.x);
      b4.y = f2bf(v.y);
      b4.z = f2bf(v.z);
      b4.w = f2bf(v.w);
      *(ushort4*)&lA[arow[s] * BK + akq[s] * 4] = b4;
    }
    __syncthreads();  // drains vmcnt (global_load_lds) + lgkm (ds_write)

    short8 af[4], bfr[4];
    for (int i = 0; i < 4; ++i)
      af[i] = *(const short8*)&lA[(wm + i * 16 + lm) * BK + quad * 8];
    for (int j = 0; j < 4; ++j)
      bfr[j] = *(const short8*)&lB[(wn + j * 16 + lm) * BK + quad * 8];
    for (int i = 0; i < 4; ++i)
      for (int j = 0; j < 4; ++j)
        acc[i][j] =
            __builtin_amdgcn_mfma_f32_16x16x32_bf16(af[i], bfr[j], acc[i][j], 0, 0, 0);
  }

  // epilogue: h = relu(acc + b1[e]), store bf16 to hbuf at sorted positions
  // C/D layout: col = lane&15, row = quad*4 + reg
  const int cnt_rel = cnt - m0;
  for (int j = 0; j < 4; ++j) {
    int col = n0 + wn + j * 16 + lm;
    float bias = b1[e * N_H + col];
    for (int i = 0; i < 4; ++i) {
      int rbase = wm + i * 16 + quad * 4;
      f32x4 a = acc[i][j];
      for (int r = 0; r < 4; ++r) {
        int mrel = rbase + r;
        if (mrel < cnt_rel) {
          float h = a[r] + bias;
          h = h > 0.f ? h : 0.f;
          hbuf[(size_t)(off + m0 + mrel) * N_H + col] = f2bf(h);
        }
      }
    }
  }
}

// ---------------- layer 2: y = h @ W2[e] + b2[e], scatter to token row ------

__global__ __launch_bounds__(256) void k_layer2(
    const unsigned short* __restrict__ hbuf, const int* __restrict__ sorted,
    const int* __restrict__ cidx, const float* __restrict__ W2,
    const float* __restrict__ b2, float* __restrict__ out, int n) {
  int p = blockIdx.x * 4 + (threadIdx.x >> 6);
  if (p >= n) return;
  int lane = threadIdx.x & 63;
  int token = sorted[p];
  int e = cidx[token];
  e = e < 0 ? 0 : (e >= N_E ? N_E - 1 : e);
  const unsigned short* hrow = hbuf + (size_t)p * N_H;
  const float* w2e = W2 + (size_t)e * N_H * N_C;
  float a0 = 0.f, a1 = 0.f;
  for (int it = 0; it < N_H / 128; ++it) {
    int col = it * 128 + lane * 2;
    unsigned v = *(const unsigned*)&hrow[col];
    float h0 = bf2f((unsigned short)(v & 0xFFFFu));
    float h1 = bf2f((unsigned short)(v >> 16));
    float4 w = *(const float4*)&w2e[col * 2];  // rows col,col+1 (C=2)
    a0 += h0 * w.x + h1 * w.z;
    a1 += h0 * w.y + h1 * w.w;
  }
  for (int s = 32; s >= 1; s >>= 1) {
    a0 += __shfl_xor(a0, s, 64);
    a1 += __shfl_xor(a1, s, 64);
  }
  if (lane == 0) {
    out[(size_t)token * N_C + 0] = a0 + b2[e * N_C + 0];
    out[(size_t)token * N_C + 1] = a1 + b2[e * N_C + 1];
  }
}

// ---------------- launch ----------------

extern "C" void kernel_launch(void* const* d_in, const int* in_sizes, int n_in,
                              void* d_out, int out_size, void* d_ws, size_t ws_size,
                              hipStream_t stream) {
  const float* emb = (const float*)d_in[0];
  const int* cidx = (const int*)d_in[1];
  const float* W1 = (const float*)d_in[2];
  const float* b1 = (const float*)d_in[3];
  const float* W2 = (const float*)d_in[4];
  const float* b2 = (const float*)d_in[5];
  float* out = (float*)d_out;
  const int n = in_sizes[1];  // token count

  // ws layout (needs ~49 MB):
  //   [0,1024): counts@0, offsets@256, cursor@512 (zeroed each call)
  //   [1024, +n*4): sorted token ids
  //   W1t bf16: E*H*D*2 = 23.6 MB
  //   hbuf bf16: n*H*2  = 25.2 MB
  char* ws = (char*)d_ws;
  int* counts = (int*)ws;
  int* offsets = (int*)(ws + 256);
  int* cursor = (int*)(ws + 512);
  int* sorted = (int*)(ws + 1024);
  size_t sorted_bytes = ((size_t)n * 4 + 1023) & ~(size_t)1023;
  unsigned short* W1t = (unsigned short*)(ws + 1024 + sorted_bytes);
  unsigned short* hbuf =
      (unsigned short*)((char*)W1t + (size_t)N_E * N_D * N_H * 2);

  hipMemsetAsync(d_ws, 0, 1024, stream);
  int nb = (n + 255) / 256;
  k_hist<<<nb, 256, 0, stream>>>(cidx, counts, n);
  k_scan<<<1, 64, 0, stream>>>(counts, offsets, cursor);
  k_scatter<<<nb, 256, 0, stream>>>(cidx, cursor, sorted, n);
  k_w1_cvt<<<dim3(N_H / 32, N_D / 32, N_E), 256, 0, stream>>>(W1, W1t);
  k_gemm1<<<dim3(N_H / NT, (n + MT - 1) / MT, N_E), 256, 0, stream>>>(
      emb, b1, W1t, sorted, counts, offsets, hbuf);
  k_layer2<<<(n + 3) / 4, 256, 0, stream>>>(hbuf, sorted, cidx, W2, b2, out, n);
}

// Round 2
// 224.012 us; speedup vs baseline: 1.0856x; 1.0856x over previous
//
#include <hip/hip_runtime.h>

// DHSMoEDetector: N=16384 tokens, D=768, H=768, C=2, E=20
#define N_D 768
#define N_H 768
#define N_C 2
#define N_E 20
#define MT 128
#define NT 128
#define BK 32
#define MAX_TILES 160

typedef __attribute__((ext_vector_type(8))) short short8;
typedef __attribute__((ext_vector_type(4))) float f32x4;

__device__ __forceinline__ unsigned short f2bf(float f) {
  unsigned u = __builtin_bit_cast(unsigned, f);
  u += 0x7FFFu + ((u >> 16) & 1u);
  return (unsigned short)(u >> 16);
}

#define GLD_LDS16(gp, lp)                                                        \
  __builtin_amdgcn_global_load_lds(                                              \
      (const __attribute__((address_space(1))) void*)(gp),                       \
      (__attribute__((address_space(3))) void*)(lp), 16, 0, 0)

// ---------------- sort-by-expert ----------------

__global__ __launch_bounds__(256) void k_hist(const int* __restrict__ cidx,
                                              int* __restrict__ counts, int n) {
  __shared__ int lc[N_E];
  if (threadIdx.x < N_E) lc[threadIdx.x] = 0;
  __syncthreads();
  for (int i = blockIdx.x * blockDim.x + threadIdx.x; i < n;
       i += gridDim.x * blockDim.x) {
    int e = cidx[i];
    e = e < 0 ? 0 : (e >= N_E ? N_E - 1 : e);
    atomicAdd(&lc[e], 1);
  }
  __syncthreads();
  if (threadIdx.x < N_E) atomicAdd(&counts[threadIdx.x], lc[threadIdx.x]);
}

// single-thread scan + tile-table build (20 experts — trivial)
__global__ void k_scan(const int* __restrict__ counts, int* __restrict__ offsets,
                       int* __restrict__ cursor, int* __restrict__ tiles,
                       int* __restrict__ numTiles) {
  if (threadIdx.x == 0) {
    int run = 0, t = 0;
    for (int e = 0; e < N_E; ++e) {
      offsets[e] = run;
      cursor[e] = run;
      int nt = (counts[e] + MT - 1) / MT;
      for (int m = 0; m < nt && t < MAX_TILES; ++m) tiles[t++] = (e << 8) | m;
      run += counts[e];
    }
    *numTiles = t;
  }
}

__global__ __launch_bounds__(256) void k_scatter(const int* __restrict__ cidx,
                                                 int* __restrict__ cursor,
                                                 int* __restrict__ sorted, int n) {
  __shared__ int lc[N_E];
  __shared__ int lbase[N_E];
  int tid = threadIdx.x;
  if (tid < N_E) lc[tid] = 0;
  __syncthreads();
  int i = blockIdx.x * blockDim.x + tid;
  int e = 0, p = 0;
  if (i < n) {
    e = cidx[i];
    e = e < 0 ? 0 : (e >= N_E ? N_E - 1 : e);
    p = atomicAdd(&lc[e], 1);
  }
  __syncthreads();
  if (tid < N_E) lbase[tid] = atomicAdd(&cursor[tid], lc[tid]);
  __syncthreads();
  if (i < n) sorted[lbase[e] + p] = i;
}

// ---------------- gather embeddings into sorted order, fp32 -> bf16 --------
// one block per output row (192 threads = 192 float4 = 768 elements)

__global__ __launch_bounds__(192) void k_gather(const float* __restrict__ emb,
                                                const int* __restrict__ sorted,
                                                unsigned short* __restrict__ Xg,
                                                int n) {
  int row = blockIdx.x;
  int j = threadIdx.x;
  ushort4 o;
  if (row < n) {
    float4 v = ((const float4*)(emb + (size_t)sorted[row] * N_D))[j];
    o.x = f2bf(v.x);
    o.y = f2bf(v.y);
    o.z = f2bf(v.z);
    o.w = f2bf(v.w);
  } else {
    o.x = o.y = o.z = o.w = 0;  // zero pad tail so GEMM padding rows are finite
  }
  ((ushort4*)(Xg + (size_t)row * N_D))[j] = o;
}

// ---------------- W1 (E,D,H) fp32 -> W1t (E,H,D) bf16 (vectorized) ---------

__global__ __launch_bounds__(256) void k_w1_cvt(const float* __restrict__ W1,
                                                unsigned short* __restrict__ W1t) {
  __shared__ float tile[64][65];
  int e = blockIdx.z, h0 = blockIdx.x * 64, d0 = blockIdx.y * 64;
  const float* src = W1 + (size_t)e * N_D * N_H;
  unsigned short* dst = W1t + (size_t)e * N_H * N_D;
  int tx = threadIdx.x & 15, ty = threadIdx.x >> 4;
  for (int s = 0; s < 4; ++s) {
    int d = s * 16 + ty;
    float4 v = *(const float4*)&src[(size_t)(d0 + d) * N_H + h0 + tx * 4];
    tile[d][tx * 4 + 0] = v.x;
    tile[d][tx * 4 + 1] = v.y;
    tile[d][tx * 4 + 2] = v.z;
    tile[d][tx * 4 + 3] = v.w;
  }
  __syncthreads();
  for (int s = 0; s < 4; ++s) {
    int h = s * 16 + ty;
    ushort4 o;
    o.x = f2bf(tile[tx * 4 + 0][h]);
    o.y = f2bf(tile[tx * 4 + 1][h]);
    o.z = f2bf(tile[tx * 4 + 2][h]);
    o.w = f2bf(tile[tx * 4 + 3][h]);
    *(ushort4*)&dst[(size_t)(h0 + h) * N_D + d0 + tx * 4] = o;
  }
}

// ---------------- fused grouped GEMM1 + relu + layer2 ----------------------
// m97 structure: both operands via global_load_lds width=16; epilogue computes
// y += relu(h)·W2[e] partials and atomically accumulates into out.

__global__ __launch_bounds__(256, 2) void k_gemm(
    const unsigned short* __restrict__ Xg, const unsigned short* __restrict__ W1t,
    const float* __restrict__ b1, const float* __restrict__ W2,
    const float* __restrict__ b2, const int* __restrict__ sorted,
    const int* __restrict__ counts, const int* __restrict__ offsets,
    const int* __restrict__ tiles, const int* __restrict__ numTiles,
    float* __restrict__ out) {
  if ((int)blockIdx.y >= *numTiles) return;
  const int tv = tiles[blockIdx.y];
  const int e = tv >> 8;
  const int m0 = (tv & 255) * MT;
  const int off = offsets[e];
  const int cnt_rel = counts[e] - m0;
  const int n0 = blockIdx.x * NT;

  __shared__ unsigned short lA[MT * BK];  // [m][k] 8KB
  __shared__ unsigned short lB[NT * BK];  // [n][k] 8KB

  const int tid = threadIdx.x;
  const int wid = tid >> 6, lane = tid & 63;
  const int wm = (wid >> 1) * 64, wn = (wid & 1) * 64;
  const int quad = lane >> 4, lm = lane & 15;

  // staging: wave w stages rows [w*32, w*32+32) of A and B tiles.
  // chunk = 16 rows x 64B; lane l -> row l>>2, k-offset (l&3)*8 elements.
  const unsigned short* ag =
      Xg + (size_t)(off + m0 + wid * 32 + (lane >> 2)) * N_D + (lane & 3) * 8;
  const unsigned short* bg = W1t + (size_t)e * N_H * N_D +
                             (size_t)(n0 + wid * 32 + (lane >> 2)) * N_D +
                             (lane & 3) * 8;

  f32x4 acc[4][4] = {};

  for (int kt = 0; kt < N_D / BK; ++kt) {
    __syncthreads();  // previous iter's ds_reads done before overwrite
    const unsigned short* agk = ag + kt * BK;
    const unsigned short* bgk = bg + kt * BK;
    GLD_LDS16(agk, &lA[(wid * 32) * BK]);
    GLD_LDS16(agk + 16 * N_D, &lA[(wid * 32 + 16) * BK]);
    GLD_LDS16(bgk, &lB[(wid * 32) * BK]);
    GLD_LDS16(bgk + 16 * N_D, &lB[(wid * 32 + 16) * BK]);
    __syncthreads();  // drains vmcnt (global_load_lds)

    short8 af[4], bfr[4];
    for (int i = 0; i < 4; ++i)
      af[i] = *(const short8*)&lA[(wm + i * 16 + lm) * BK + quad * 8];
    for (int j = 0; j < 4; ++j)
      bfr[j] = *(const short8*)&lB[(wn + j * 16 + lm) * BK + quad * 8];
    for (int i = 0; i < 4; ++i)
      for (int j = 0; j < 4; ++j)
        acc[i][j] =
            __builtin_amdgcn_mfma_f32_16x16x32_bf16(af[i], bfr[j], acc[i][j], 0, 0, 0);
  }

  // ---- fused epilogue: h = relu(acc + b1), y-partial = h * W2[e] ----
  // C/D layout: col = lane&15 (lm), row = quad*4 + reg
  float y0[4][4], y1[4][4];
  for (int i = 0; i < 4; ++i)
    for (int r = 0; r < 4; ++r) y0[i][r] = y1[i][r] = 0.f;

  for (int j = 0; j < 4; ++j) {
    int col = n0 + wn + j * 16 + lm;
    float bias = b1[e * N_H + col];
    float2 w2 = *(const float2*)&W2[((size_t)e * N_H + col) * N_C];
    for (int i = 0; i < 4; ++i) {
      f32x4 a = acc[i][j];
      for (int r = 0; r < 4; ++r) {
        float h = a[r] + bias;
        h = h > 0.f ? h : 0.f;
        y0[i][r] += h * w2.x;
        y1[i][r] += h * w2.y;
      }
    }
  }
  // reduce across the 16 col-lanes (lm); quad (bits 4-5) preserved by xor<16
  for (int s = 1; s < 16; s <<= 1) {
    for (int i = 0; i < 4; ++i)
      for (int r = 0; r < 4; ++r) {
        y0[i][r] += __shfl_xor(y0[i][r], s, 64);
        y1[i][r] += __shfl_xor(y1[i][r], s, 64);
      }
  }
  if (lm == 0) {
    const bool add_bias = (n0 == 0) && (wn == 0);  // exactly once per row
    float bb0 = add_bias ? b2[e * N_C + 0] : 0.f;
    float bb1 = add_bias ? b2[e * N_C + 1] : 0.f;
    for (int i = 0; i < 4; ++i) {
      for (int r = 0; r < 4; ++r) {
        int mrel = wm + i * 16 + quad * 4 + r;
        if (mrel < cnt_rel) {
          int token = sorted[off + m0 + mrel];
          atomicAdd(&out[(size_t)token * N_C + 0], y0[i][r] + bb0);
          atomicAdd(&out[(size_t)token * N_C + 1], y1[i][r] + bb1);
        }
      }
    }
  }
}

// ---------------- launch ----------------

extern "C" void kernel_launch(void* const* d_in, const int* in_sizes, int n_in,
                              void* d_out, int out_size, void* d_ws, size_t ws_size,
                              hipStream_t stream) {
  const float* emb = (const float*)d_in[0];
  const int* cidx = (const int*)d_in[1];
  const float* W1 = (const float*)d_in[2];
  const float* b1 = (const float*)d_in[3];
  const float* W2 = (const float*)d_in[4];
  const float* b2 = (const float*)d_in[5];
  float* out = (float*)d_out;
  const int n = in_sizes[1];

  // ws layout (~49.1 MB):
  //   0: counts[32] | 128: offsets[32] | 256: cursor[32] | 384: numTiles
  //   512: tiles[160] | 2048: sorted[n] | then Xg bf16 (n+128)*768, W1t bf16
  char* ws = (char*)d_ws;
  int* counts = (int*)ws;
  int* offsets = (int*)(ws + 128);
  int* cursor = (int*)(ws + 256);
  int* numTiles = (int*)(ws + 384);
  int* tiles = (int*)(ws + 512);
  int* sorted = (int*)(ws + 2048);
  size_t sorted_bytes = ((size_t)n * 4 + 255) & ~(size_t)255;
  unsigned short* Xg = (unsigned short*)(ws + 2048 + sorted_bytes);
  int pcap = n + MT;  // zero-padded tail rows
  unsigned short* W1t = Xg + (size_t)pcap * N_D;

  hipMemsetAsync(d_ws, 0, 2048, stream);
  hipMemsetAsync(d_out, 0, (size_t)out_size * sizeof(float), stream);
  int nb = (n + 255) / 256;
  k_hist<<<nb, 256, 0, stream>>>(cidx, counts, n);
  k_scan<<<1, 64, 0, stream>>>(counts, offsets, cursor, tiles, numTiles);
  k_scatter<<<nb, 256, 0, stream>>>(cidx, cursor, sorted, n);
  k_gather<<<pcap, 192, 0, stream>>>(emb, sorted, Xg, n);
  k_w1_cvt<<<dim3(N_H / 64, N_D / 64, N_E), 256, 0, stream>>>(W1, W1t);
  k_gemm<<<dim3(N_H / NT, MAX_TILES), 256, 0, stream>>>(
      Xg, W1t, b1, W2, b2, sorted, counts, offsets, tiles, numTiles, out);
}

// Round 3
// 223.466 us; speedup vs baseline: 1.0882x; 1.0024x over previous
//
#include <hip/hip_runtime.h>

// DHSMoEDetector: N=16384 tokens, D=768, H=768, C=2, E=20
#define N_D 768
#define N_H 768
#define N_C 2
#define N_E 20
#define MT 128
#define NT 128
#define BK 32
#define KT (N_D / BK)
#define MAX_TILES 160

typedef __attribute__((ext_vector_type(8))) short short8;
typedef __attribute__((ext_vector_type(4))) float f32x4;

__device__ __forceinline__ unsigned short f2bf(float f) {
  unsigned u = __builtin_bit_cast(unsigned, f);
  u += 0x7FFFu + ((u >> 16) & 1u);
  return (unsigned short)(u >> 16);
}

#define GLD_LDS16(gp, lp)                                                        \
  __builtin_amdgcn_global_load_lds(                                              \
      (const __attribute__((address_space(1))) void*)(gp),                       \
      (__attribute__((address_space(3))) void*)(lp), 16, 0, 0)

// ---------------- sort-by-expert ----------------

__global__ __launch_bounds__(256) void k_hist(const int* __restrict__ cidx,
                                              int* __restrict__ counts, int n) {
  __shared__ int lc[N_E];
  if (threadIdx.x < N_E) lc[threadIdx.x] = 0;
  __syncthreads();
  for (int i = blockIdx.x * blockDim.x + threadIdx.x; i < n;
       i += gridDim.x * blockDim.x) {
    int e = cidx[i];
    e = e < 0 ? 0 : (e >= N_E ? N_E - 1 : e);
    atomicAdd(&lc[e], 1);
  }
  __syncthreads();
  if (threadIdx.x < N_E) atomicAdd(&counts[threadIdx.x], lc[threadIdx.x]);
}

__global__ void k_scan(const int* __restrict__ counts, int* __restrict__ offsets,
                       int* __restrict__ cursor, int* __restrict__ tiles,
                       int* __restrict__ numTiles) {
  if (threadIdx.x == 0) {
    int run = 0, t = 0;
    for (int e = 0; e < N_E; ++e) {
      offsets[e] = run;
      cursor[e] = run;
      int nt = (counts[e] + MT - 1) / MT;
      for (int m = 0; m < nt && t < MAX_TILES; ++m) tiles[t++] = (e << 8) | m;
      run += counts[e];
    }
    *numTiles = t;
  }
}

__global__ __launch_bounds__(256) void k_scatter(const int* __restrict__ cidx,
                                                 int* __restrict__ cursor,
                                                 int* __restrict__ sorted, int n) {
  __shared__ int lc[N_E];
  __shared__ int lbase[N_E];
  int tid = threadIdx.x;
  if (tid < N_E) lc[tid] = 0;
  __syncthreads();
  int i = blockIdx.x * blockDim.x + tid;
  int e = 0, p = 0;
  if (i < n) {
    e = cidx[i];
    e = e < 0 ? 0 : (e >= N_E ? N_E - 1 : e);
    p = atomicAdd(&lc[e], 1);
  }
  __syncthreads();
  if (tid < N_E) lbase[tid] = atomicAdd(&cursor[tid], lc[tid]);
  __syncthreads();
  if (i < n) sorted[lbase[e] + p] = i;
}

// ---------------- gather embeddings into sorted order, fp32 -> bf16 --------

__global__ __launch_bounds__(192) void k_gather(const float* __restrict__ emb,
                                                const int* __restrict__ sorted,
                                                unsigned short* __restrict__ Xg,
                                                int n) {
  int row = blockIdx.x;
  int j = threadIdx.x;
  ushort4 o;
  if (row < n) {
    float4 v = ((const float4*)(emb + (size_t)sorted[row] * N_D))[j];
    o.x = f2bf(v.x);
    o.y = f2bf(v.y);
    o.z = f2bf(v.z);
    o.w = f2bf(v.w);
  } else {
    o.x = o.y = o.z = o.w = 0;
  }
  ((ushort4*)(Xg + (size_t)row * N_D))[j] = o;
}

// ---------------- W1 (E,D,H) fp32 -> W1t (E,H,D) bf16, 16B stores ----------

__global__ __launch_bounds__(256) void k_w1_cvt(const float* __restrict__ W1,
                                                unsigned short* __restrict__ W1t) {
  __shared__ float tile[64][65];
  int e = blockIdx.z, h0 = blockIdx.x * 64, d0 = blockIdx.y * 64;
  const float* src = W1 + (size_t)e * N_D * N_H;
  unsigned short* dst = W1t + (size_t)e * N_H * N_D;
  int tx = threadIdx.x & 15, ty = threadIdx.x >> 4;
  for (int s = 0; s < 4; ++s) {
    int d = s * 16 + ty;
    float4 v = *(const float4*)&src[(size_t)(d0 + d) * N_H + h0 + tx * 4];
    tile[d][tx * 4 + 0] = v.x;
    tile[d][tx * 4 + 1] = v.y;
    tile[d][tx * 4 + 2] = v.z;
    tile[d][tx * 4 + 3] = v.w;
  }
  __syncthreads();
  int px = threadIdx.x & 7, py = threadIdx.x >> 3;  // 8 x ushort8 per row, 32 rows/pass
  for (int s = 0; s < 2; ++s) {
    int h = s * 32 + py;
    short8 v;
    for (int j = 0; j < 8; ++j)
      v[j] = (short)f2bf(tile[px * 8 + j][h]);
    *(short8*)&dst[(size_t)(h0 + h) * N_D + d0 + px * 8] = v;
  }
}

// ---------------- fused grouped GEMM1 + relu + layer2 ----------------------
// Double-buffered LDS: prefetch kt+1 issued at iter top, single barrier per
// iter (the compiler's forced vmcnt(0) before s_barrier then lands AFTER the
// ds_read+MFMA work, hiding most of the load latency). 16B-chunk XOR swizzle
// on the global source side breaks ds_read_b128 bank conflicts.

__global__ __launch_bounds__(256, 2) void k_gemm(
    const unsigned short* __restrict__ Xg, const unsigned short* __restrict__ W1t,
    const float* __restrict__ b1, const float* __restrict__ W2,
    const float* __restrict__ b2, const int* __restrict__ sorted,
    const int* __restrict__ counts, const int* __restrict__ offsets,
    const int* __restrict__ tiles, const int* __restrict__ numTiles,
    float* __restrict__ out) {
  if ((int)blockIdx.y >= *numTiles) return;
  const int tv = tiles[blockIdx.y];
  const int e = tv >> 8;
  const int m0 = (tv & 255) * MT;
  const int off = offsets[e];
  const int cnt_rel = counts[e] - m0;
  const int n0 = blockIdx.x * NT;

  __shared__ unsigned short lA[2][MT * BK];  // 2 x 8KB
  __shared__ unsigned short lB[2][NT * BK];  // 2 x 8KB

  const int tid = threadIdx.x;
  const int wid = tid >> 6, lane = tid & 63;
  const int wm = (wid >> 1) * 64, wn = (wid & 1) * 64;
  const int quad = lane >> 4, lm = lane & 15;

  // staging: wave w stages rows [w*32, w*32+32). Global source chunk is
  // XOR-swizzled: lane l reads chunk (l&3)^(row&3) so LDS chunk c of row r
  // holds global k-chunk c^(r&3).
  const int srow = lane >> 2;
  const int schunk = (lane & 3) ^ (srow & 3);
  const unsigned short* ag =
      Xg + (size_t)(off + m0 + wid * 32 + srow) * N_D + schunk * 8;
  const unsigned short* bg = W1t + (size_t)e * N_H * N_D +
                             (size_t)(n0 + wid * 32 + srow) * N_D + schunk * 8;
  unsigned short* lAw0 = &lA[0][(wid * 32) * BK];
  unsigned short* lAw1 = &lA[1][(wid * 32) * BK];
  unsigned short* lBw0 = &lB[0][(wid * 32) * BK];
  unsigned short* lBw1 = &lB[1][(wid * 32) * BK];

  // fragment-read chunk swizzle (involution of the store swizzle)
  const int koff = (quad ^ (lm & 3)) * 8;

  f32x4 acc[4][4] = {};

  // prologue: stage kt=0 into buffer 0
  {
    GLD_LDS16(ag, lAw0);
    GLD_LDS16(ag + 16 * N_D, lAw0 + 16 * BK);
    GLD_LDS16(bg, lBw0);
    GLD_LDS16(bg + 16 * N_D, lBw0 + 16 * BK);
  }

  for (int kt = 0; kt < KT; ++kt) {
    const int cur = kt & 1;
    __syncthreads();  // publishes buf[cur]; all waves done reading buf[cur^1]
    if (kt + 1 < KT) {
      const unsigned short* agk = ag + (kt + 1) * BK;
      const unsigned short* bgk = bg + (kt + 1) * BK;
      unsigned short* la = cur ? lAw0 : lAw1;
      unsigned short* lb = cur ? lBw0 : lBw1;
      GLD_LDS16(agk, la);
      GLD_LDS16(agk + 16 * N_D, la + 16 * BK);
      GLD_LDS16(bgk, lb);
      GLD_LDS16(bgk + 16 * N_D, lb + 16 * BK);
    }
    short8 af[4], bfr[4];
    for (int i = 0; i < 4; ++i)
      af[i] = *(const short8*)&lA[cur][(wm + i * 16 + lm) * BK + koff];
    for (int j = 0; j < 4; ++j)
      bfr[j] = *(const short8*)&lB[cur][(wn + j * 16 + lm) * BK + koff];
    for (int i = 0; i < 4; ++i)
      for (int j = 0; j < 4; ++j)
        acc[i][j] =
            __builtin_amdgcn_mfma_f32_16x16x32_bf16(af[i], bfr[j], acc[i][j], 0, 0, 0);
  }

  // ---- fused epilogue: h = relu(acc + b1), y-partial = h * W2[e] ----
  // C/D layout: col = lane&15 (lm), row = quad*4 + reg
  float y0[4][4], y1[4][4];
  for (int i = 0; i < 4; ++i)
    for (int r = 0; r < 4; ++r) y0[i][r] = y1[i][r] = 0.f;

  for (int j = 0; j < 4; ++j) {
    int col = n0 + wn + j * 16 + lm;
    float bias = b1[e * N_H + col];
    float2 w2 = *(const float2*)&W2[((size_t)e * N_H + col) * N_C];
    for (int i = 0; i < 4; ++i) {
      f32x4 a = acc[i][j];
      for (int r = 0; r < 4; ++r) {
        float h = a[r] + bias;
        h = h > 0.f ? h : 0.f;
        y0[i][r] += h * w2.x;
        y1[i][r] += h * w2.y;
      }
    }
  }
  for (int s = 1; s < 16; s <<= 1) {
    for (int i = 0; i < 4; ++i)
      for (int r = 0; r < 4; ++r) {
        y0[i][r] += __shfl_xor(y0[i][r], s, 64);
        y1[i][r] += __shfl_xor(y1[i][r], s, 64);
      }
  }
  if (lm == 0) {
    const bool add_bias = (n0 == 0) && (wn == 0);
    float bb0 = add_bias ? b2[e * N_C + 0] : 0.f;
    float bb1 = add_bias ? b2[e * N_C + 1] : 0.f;
    for (int i = 0; i < 4; ++i) {
      for (int r = 0; r < 4; ++r) {
        int mrel = wm + i * 16 + quad * 4 + r;
        if (mrel < cnt_rel) {
          int token = sorted[off + m0 + mrel];
          atomicAdd(&out[(size_t)token * N_C + 0], y0[i][r] + bb0);
          atomicAdd(&out[(size_t)token * N_C + 1], y1[i][r] + bb1);
        }
      }
    }
  }
}

// ---------------- launch ----------------

extern "C" void kernel_launch(void* const* d_in, const int* in_sizes, int n_in,
                              void* d_out, int out_size, void* d_ws, size_t ws_size,
                              hipStream_t stream) {
  const float* emb = (const float*)d_in[0];
  const int* cidx = (const int*)d_in[1];
  const float* W1 = (const float*)d_in[2];
  const float* b1 = (const float*)d_in[3];
  const float* W2 = (const float*)d_in[4];
  const float* b2 = (const float*)d_in[5];
  float* out = (float*)d_out;
  const int n = in_sizes[1];

  char* ws = (char*)d_ws;
  int* counts = (int*)ws;
  int* offsets = (int*)(ws + 128);
  int* cursor = (int*)(ws + 256);
  int* numTiles = (int*)(ws + 384);
  int* tiles = (int*)(ws + 512);
  int* sorted = (int*)(ws + 2048);
  size_t sorted_bytes = ((size_t)n * 4 + 255) & ~(size_t)255;
  unsigned short* Xg = (unsigned short*)(ws + 2048 + sorted_bytes);
  int pcap = n + MT;  // zero-padded tail rows
  unsigned short* W1t = Xg + (size_t)pcap * N_D;

  hipMemsetAsync(d_ws, 0, 2048, stream);
  hipMemsetAsync(d_out, 0, (size_t)out_size * sizeof(float), stream);
  int nb = (n + 255) / 256;
  k_hist<<<nb, 256, 0, stream>>>(cidx, counts, n);
  k_scan<<<1, 64, 0, stream>>>(counts, offsets, cursor, tiles, numTiles);
  k_scatter<<<nb, 256, 0, stream>>>(cidx, cursor, sorted, n);
  k_gather<<<pcap, 192, 0, stream>>>(emb, sorted, Xg, n);
  k_w1_cvt<<<dim3(N_H / 64, N_D / 64, N_E), 256, 0, stream>>>(W1, W1t);
  k_gemm<<<dim3(N_H / NT, MAX_TILES), 256, 0, stream>>>(
      Xg, W1t, b1, W2, b2, sorted, counts, offsets, tiles, numTiles, out);
}

// Round 4
// 222.507 us; speedup vs baseline: 1.0929x; 1.0043x over previous
//
#include <hip/hip_runtime.h>

// DHSMoEDetector: N=16384 tokens, D=768, H=768, C=2, E=20
#define N_D 768
#define N_H 768
#define N_C 2
#define N_E 20
#define MT 128
#define NT 128
#define BK 32
#define KT (N_D / BK)
#define MAX_TILES 160
#define ROWB (N_D * 2)  // row stride in bytes (bf16)

typedef __attribute__((ext_vector_type(8))) short short8;
typedef __attribute__((ext_vector_type(4))) float f32x4;

__device__ __forceinline__ unsigned short f2bf(float f) {
  unsigned u = __builtin_bit_cast(unsigned, f);
  u += 0x7FFFu + ((u >> 16) & 1u);
  return (unsigned short)(u >> 16);
}

#define GLD_LDS16(gp, lp)                                                        \
  __builtin_amdgcn_global_load_lds(                                              \
      (const __attribute__((address_space(1))) void*)(gp),                       \
      (__attribute__((address_space(3))) void*)(lp), 16, 0, 0)

// ---------------- sort-by-expert ----------------

__global__ __launch_bounds__(256) void k_hist(const int* __restrict__ cidx,
                                              int* __restrict__ counts, int n) {
  __shared__ int lc[N_E];
  if (threadIdx.x < N_E) lc[threadIdx.x] = 0;
  __syncthreads();
  for (int i = blockIdx.x * blockDim.x + threadIdx.x; i < n;
       i += gridDim.x * blockDim.x) {
    int e = cidx[i];
    e = e < 0 ? 0 : (e >= N_E ? N_E - 1 : e);
    atomicAdd(&lc[e], 1);
  }
  __syncthreads();
  if (threadIdx.x < N_E) atomicAdd(&counts[threadIdx.x], lc[threadIdx.x]);
}

__global__ void k_scan(const int* __restrict__ counts, int* __restrict__ offsets,
                       int* __restrict__ cursor, int* __restrict__ tiles,
                       int* __restrict__ numTiles) {
  if (threadIdx.x == 0) {
    int run = 0, t = 0;
    for (int e = 0; e < N_E; ++e) {
      offsets[e] = run;
      cursor[e] = run;
      int nt = (counts[e] + MT - 1) / MT;
      for (int m = 0; m < nt && t < MAX_TILES; ++m) tiles[t++] = (e << 8) | m;
      run += counts[e];
    }
    *numTiles = t;
  }
}

__global__ __launch_bounds__(256) void k_scatter(const int* __restrict__ cidx,
                                                 int* __restrict__ cursor,
                                                 int* __restrict__ sorted, int n) {
  __shared__ int lc[N_E];
  __shared__ int lbase[N_E];
  int tid = threadIdx.x;
  if (tid < N_E) lc[tid] = 0;
  __syncthreads();
  int i = blockIdx.x * blockDim.x + tid;
  int e = 0, p = 0;
  if (i < n) {
    e = cidx[i];
    e = e < 0 ? 0 : (e >= N_E ? N_E - 1 : e);
    p = atomicAdd(&lc[e], 1);
  }
  __syncthreads();
  if (tid < N_E) lbase[tid] = atomicAdd(&cursor[tid], lc[tid]);
  __syncthreads();
  if (i < n) sorted[lbase[e] + p] = i;
}

// ---------------- gather embeddings into sorted order, fp32 -> bf16 --------

__global__ __launch_bounds__(192) void k_gather(const float* __restrict__ emb,
                                                const int* __restrict__ sorted,
                                                unsigned short* __restrict__ Xg,
                                                int n) {
  int row = blockIdx.x;
  int j = threadIdx.x;
  ushort4 o;
  if (row < n) {
    float4 v = ((const float4*)(emb + (size_t)sorted[row] * N_D))[j];
    o.x = f2bf(v.x);
    o.y = f2bf(v.y);
    o.z = f2bf(v.z);
    o.w = f2bf(v.w);
  } else {
    o.x = o.y = o.z = o.w = 0;
  }
  ((ushort4*)(Xg + (size_t)row * N_D))[j] = o;
}

// ---------------- W1 (E,D,H) fp32 -> W1t (E,H,D) bf16, 16B stores ----------

__global__ __launch_bounds__(256) void k_w1_cvt(const float* __restrict__ W1,
                                                unsigned short* __restrict__ W1t) {
  __shared__ float tile[64][65];
  int e = blockIdx.z, h0 = blockIdx.x * 64, d0 = blockIdx.y * 64;
  const float* src = W1 + (size_t)e * N_D * N_H;
  unsigned short* dst = W1t + (size_t)e * N_H * N_D;
  int tx = threadIdx.x & 15, ty = threadIdx.x >> 4;
  for (int s = 0; s < 4; ++s) {
    int d = s * 16 + ty;
    float4 v = *(const float4*)&src[(size_t)(d0 + d) * N_H + h0 + tx * 4];
    tile[d][tx * 4 + 0] = v.x;
    tile[d][tx * 4 + 1] = v.y;
    tile[d][tx * 4 + 2] = v.z;
    tile[d][tx * 4 + 3] = v.w;
  }
  __syncthreads();
  int px = threadIdx.x & 7, py = threadIdx.x >> 3;
  for (int s = 0; s < 2; ++s) {
    int h = s * 32 + py;
    short8 v;
    for (int j = 0; j < 8; ++j)
      v[j] = (short)f2bf(tile[px * 8 + j][h]);
    *(short8*)&dst[(size_t)(h0 + h) * N_D + d0 + px * 8] = v;
  }
}

// ---------------- fused grouped GEMM1 + relu + layer2 ----------------------
// Depth-2 software pipeline with raw asm barriers: vmcnt never drains to 0
// inside the loop (batch kt waited at iter kt was issued at iter kt-2).
// LDS is chunk-major per 16-row group (lane l of each global_load_lds carries
// row l&15, k-chunk l>>4), making fragment ds_read_b128 stride-16B
// contiguous -> conflict-free (8 lanes cover all 32 banks).

__global__ __launch_bounds__(256, 2) void k_gemm(
    const unsigned short* __restrict__ Xg, const unsigned short* __restrict__ W1t,
    const float* __restrict__ b1, const float* __restrict__ W2,
    const float* __restrict__ b2, const int* __restrict__ sorted,
    const int* __restrict__ counts, const int* __restrict__ offsets,
    const int* __restrict__ tiles, const int* __restrict__ numTiles,
    float* __restrict__ out) {
  if ((int)blockIdx.y >= *numTiles) return;
  const int tv = tiles[blockIdx.y];
  const int e = tv >> 8;
  const int m0 = (tv & 255) * MT;
  const int off = offsets[e];
  const int cnt_rel = counts[e] - m0;
  const int n0 = blockIdx.x * NT;

  __shared__ unsigned short lA[2][MT * BK];  // 2 x 8KB, chunk-major groups
  __shared__ unsigned short lB[2][NT * BK];

  const int tid = threadIdx.x;
  const int wid = tid >> 6, lane = tid & 63;
  const int wm = (wid >> 1) * 64, wn = (wid & 1) * 64;
  const int quad = lane >> 4, lm = lane & 15;

  // staging lane mapping: row = lane&15 (+R0), k-chunk = lane>>4.
  // wave w stages A rows [w*32,w*32+32) and B rows likewise, 2 instrs each.
  const int R0 = wid * 32 + lm;
  const char* agp = (const char*)Xg + (size_t)(off + m0 + R0) * ROWB + quad * 16;
  const char* bgp = (const char*)W1t + (size_t)e * N_H * ROWB +
                    (size_t)(n0 + R0) * ROWB + quad * 16;
  unsigned short* lap[2] = {&lA[0][(wid * 32) * BK], &lA[1][(wid * 32) * BK]};
  unsigned short* lbp[2] = {&lB[0][(wid * 32) * BK], &lB[1][(wid * 32) * BK]};

#define ISSUE_BATCH(kk, b)                                                       \
  do {                                                                           \
    const char* a_ = agp + (kk)*64;                                              \
    const char* b_ = bgp + (kk)*64;                                              \
    GLD_LDS16(a_, lap[b]);                                                       \
    GLD_LDS16(a_ + 16 * ROWB, lap[b] + 16 * BK);                                 \
    GLD_LDS16(b_, lbp[b]);                                                       \
    GLD_LDS16(b_ + 16 * ROWB, lbp[b] + 16 * BK);                                 \
  } while (0)

  f32x4 acc[4][4] = {};

  ISSUE_BATCH(0, 0);
  ISSUE_BATCH(1, 1);

  // fragment addresses (chunk-major): row m=wm+i*16+lm, chunk=quad
  //   elem index = ((m>>4)*4 + quad)*128 + lm*8
  const int fa = quad * 128 + lm * 8;

  for (int kt = 0; kt < KT; ++kt) {
    const int cur = kt & 1;
    asm volatile("s_waitcnt vmcnt(4)\n\ts_barrier" ::: "memory");
    short8 af[4], bfr[4];
    for (int i = 0; i < 4; ++i)
      af[i] = *(const short8*)&lA[cur][((wm >> 4) + i) * 512 + fa];
    for (int j = 0; j < 4; ++j)
      bfr[j] = *(const short8*)&lB[cur][((wn >> 4) + j) * 512 + fa];
    asm volatile("s_waitcnt lgkmcnt(0)\n\ts_barrier" ::: "memory");
    int kk = kt + 2;
    if (kk >= KT) kk -= KT;  // dummy re-load keeps vmcnt bookkeeping uniform
    ISSUE_BATCH(kk, cur);
    for (int i = 0; i < 4; ++i)
      for (int j = 0; j < 4; ++j)
        acc[i][j] =
            __builtin_amdgcn_mfma_f32_16x16x32_bf16(af[i], bfr[j], acc[i][j], 0, 0, 0);
  }

  // ---- fused epilogue: h = relu(acc + b1), y-partial = h * W2[e] ----
  // C/D layout: col = lane&15 (lm), row = quad*4 + reg
  float y0[4][4], y1[4][4];
  for (int i = 0; i < 4; ++i)
    for (int r = 0; r < 4; ++r) y0[i][r] = y1[i][r] = 0.f;

  for (int j = 0; j < 4; ++j) {
    int col = n0 + wn + j * 16 + lm;
    float bias = b1[e * N_H + col];
    float2 w2 = *(const float2*)&W2[((size_t)e * N_H + col) * N_C];
    for (int i = 0; i < 4; ++i) {
      f32x4 a = acc[i][j];
      for (int r = 0; r < 4; ++r) {
        float h = a[r] + bias;
        h = h > 0.f ? h : 0.f;
        y0[i][r] += h * w2.x;
        y1[i][r] += h * w2.y;
      }
    }
  }
  for (int s = 1; s < 16; s <<= 1) {
    for (int i = 0; i < 4; ++i)
      for (int r = 0; r < 4; ++r) {
        y0[i][r] += __shfl_xor(y0[i][r], s, 64);
        y1[i][r] += __shfl_xor(y1[i][r], s, 64);
      }
  }
  if (lm == 0) {
    const bool add_bias = (n0 == 0) && (wn == 0);
    float bb0 = add_bias ? b2[e * N_C + 0] : 0.f;
    float bb1 = add_bias ? b2[e * N_C + 1] : 0.f;
    for (int i = 0; i < 4; ++i) {
      for (int r = 0; r < 4; ++r) {
        int mrel = wm + i * 16 + quad * 4 + r;
        if (mrel < cnt_rel) {
          int token = sorted[off + m0 + mrel];
          atomicAdd(&out[(size_t)token * N_C + 0], y0[i][r] + bb0);
          atomicAdd(&out[(size_t)token * N_C + 1], y1[i][r] + bb1);
        }
      }
    }
  }
}

// ---------------- launch ----------------

extern "C" void kernel_launch(void* const* d_in, const int* in_sizes, int n_in,
                              void* d_out, int out_size, void* d_ws, size_t ws_size,
                              hipStream_t stream) {
  const float* emb = (const float*)d_in[0];
  const int* cidx = (const int*)d_in[1];
  const float* W1 = (const float*)d_in[2];
  const float* b1 = (const float*)d_in[3];
  const float* W2 = (const float*)d_in[4];
  const float* b2 = (const float*)d_in[5];
  float* out = (float*)d_out;
  const int n = in_sizes[1];

  char* ws = (char*)d_ws;
  int* counts = (int*)ws;
  int* offsets = (int*)(ws + 128);
  int* cursor = (int*)(ws + 256);
  int* numTiles = (int*)(ws + 384);
  int* tiles = (int*)(ws + 512);
  int* sorted = (int*)(ws + 2048);
  size_t sorted_bytes = ((size_t)n * 4 + 255) & ~(size_t)255;
  unsigned short* Xg = (unsigned short*)(ws + 2048 + sorted_bytes);
  int pcap = n + MT;  // zero-padded tail rows
  unsigned short* W1t = Xg + (size_t)pcap * N_D;

  hipMemsetAsync(d_ws, 0, 2048, stream);
  hipMemsetAsync(d_out, 0, (size_t)out_size * sizeof(float), stream);
  int nb = (n + 255) / 256;
  k_hist<<<nb, 256, 0, stream>>>(cidx, counts, n);
  k_scan<<<1, 64, 0, stream>>>(counts, offsets, cursor, tiles, numTiles);
  k_scatter<<<nb, 256, 0, stream>>>(cidx, cursor, sorted, n);
  k_gather<<<pcap, 192, 0, stream>>>(emb, sorted, Xg, n);
  k_w1_cvt<<<dim3(N_H / 64, N_D / 64, N_E), 256, 0, stream>>>(W1, W1t);
  k_gemm<<<dim3(N_H / NT, MAX_TILES), 256, 0, stream>>>(
      Xg, W1t, b1, W2, b2, sorted, counts, offsets, tiles, numTiles, out);
}